// Round 13
// baseline (316.822 us; speedup 1.0000x reference)
//
#include <hip/hip_runtime.h>

// GIN regressor: 3x [segment-sum aggregation -> (1+eps)*x+agg -> Linear/ReLU/Linear]
// -> global mean pool -> fc.
// r13: dispatch-graph compaction. front_kernel = LDS-binned bucket sort UNION all
// setup (xbf cast / gstart / weff / wprep) so setup hides under bucketing.
// degscat computes its own bucket-prefix (no separate scan). The layer-2 fused
// pool GEMM finalizes out[] via a last-block completion counter. 11 dispatches.
// Feature tables FEATURE-SLICED [4][N][32] bf16 (3.2MB/slice, L2-resident;
// blockIdx&3 spreads slices across XCDs). Agg: uint4/lane, 4-lane groups,
// 8-deep unroll (latency-bound regime). GEMMs = bf16 MFMA, pre-swizzled W.

#define FEAT 128
#define BCAP 2048          // per-bucket capacity (mean load ~1024)
#define CHUNK 10240        // edges per bucket block

typedef short  bf16x8 __attribute__((ext_vector_type(8)));
typedef float  f32x4  __attribute__((ext_vector_type(4)));

__device__ inline unsigned short f2bf(float f) {  // round-to-nearest-even fp32->bf16
    unsigned int u = __float_as_uint(f);
    u = (u + 0x7FFFu + ((u >> 16) & 1u)) >> 16;
    return (unsigned short)u;
}
__device__ inline float2 bfpair(unsigned int u) { // packed 2x bf16 -> 2x fp32
    float2 r;
    r.x = __uint_as_float(u << 16);
    r.y = __uint_as_float(u & 0xffff0000u);
    return r;
}

// ---------------- front: bucket sort (blocks < nchunks) + setup (rest) -------
__global__ __launch_bounds__(1024) void front_kernel(
    const int* __restrict__ src, const int* __restrict__ dst,
    int* __restrict__ bcnt, unsigned int* __restrict__ bpairs, int E, int nchunks,
    const float* __restrict__ x, unsigned int* __restrict__ xbf, long pairs, int nxbf,
    const int* __restrict__ batch, int* __restrict__ gstart, int n, int G,
    const float* __restrict__ W2f, const float* __restrict__ b2f,
    const float* __restrict__ fcw, float* __restrict__ weff,
    const float* __restrict__ W0, const float* __restrict__ W1,
    const float* __restrict__ W2, const float* __restrict__ W3,
    const float* __restrict__ W4, unsigned short* __restrict__ Wswz) {
    __shared__ unsigned int lpairs[CHUNK];   // 40KB
    __shared__ int lbase[1025];
    __shared__ int lcur[1024];
    __shared__ int lres[1024];
    __shared__ int part[1024];
    int b = blockIdx.x, tid = threadIdx.x;

    if (b < nchunks) {                   // ---- LDS-binned bucket sort chunk ----
        int e0 = b * CHUNK;
        int e1 = e0 + CHUNK; if (e1 > E) e1 = E;
        int cnt = e1 - e0;
        lcur[tid] = 0;
        __syncthreads();
        for (int e = e0 + tid; e < e1; e += 1024) atomicAdd(&lcur[dst[e] >> 6], 1);
        __syncthreads();
        int v = lcur[tid];
        part[tid] = v;
        __syncthreads();
        for (int d = 1; d < 1024; d <<= 1) {
            int u = (tid >= d) ? part[tid - d] : 0;
            __syncthreads();
            part[tid] += u;
            __syncthreads();
        }
        int ex = part[tid] - v;
        lbase[tid] = ex;
        if (tid == 1023) lbase[1024] = part[1023];
        lcur[tid] = ex;
        lres[tid] = (v > 0) ? atomicAdd(&bcnt[tid * 16], v) : 0;
        __syncthreads();
        for (int e = e0 + tid; e < e1; e += 1024) {
            int d = dst[e], s = src[e];
            int p = atomicAdd(&lcur[d >> 6], 1);
            lpairs[p] = ((unsigned int)s << 6) | (unsigned int)(d & 63);
        }
        __syncthreads();
        for (int j = tid; j < cnt; j += 1024) {
            int lo = 0, hi = 1023;
            while (lo < hi) { int m = (lo + hi + 1) >> 1; if (lbase[m] <= j) lo = m; else hi = m - 1; }
            int gpos = lres[lo] + (j - lbase[lo]);
            if (gpos < BCAP) bpairs[(size_t)lo * BCAP + gpos] = lpairs[j];
        }
        return;
    }
    b -= nchunks;
    if (b < nxbf) {                      // ---- cast x -> sliced packed bf16 ----
        long i = (long)b * 1024 + tid;   // i = node*64 + dword index
        if (i < pairs) {
            float2 v = ((const float2*)x)[i];
            unsigned int pk = (unsigned int)f2bf(v.x) | ((unsigned int)f2bf(v.y) << 16);
            long node = i >> 6;
            int dg = (int)(i & 63);
            int slice = dg >> 4, d = dg & 15;
            xbf[(size_t)slice * n * 16 + node * 16 + d] = pk;
        }
        return;
    }
    b -= nxbf;
    if (b == 0) {                        // ---- gstart[g] = lower_bound(batch, g) ----
        for (int i = tid; i <= G; i += 1024) {
            int lo = 0, hi = n;
            while (lo < hi) { int m = (lo + hi) >> 1; if (batch[m] < i) lo = m + 1; else hi = m; }
            gstart[i] = lo;
        }
        return;
    }
    if (b == 1) {                        // ---- weff = W2@fcw ; weff[128] = b2.fcw ----
        int lane = tid & 63, wave = tid >> 6;   // 16 waves
        float2 f2 = ((const float2*)fcw)[lane];
        for (int r = wave; r < 128; r += 16) {
            float2 w = ((const float2*)(W2f + r * FEAT))[lane];
            float d = w.x * f2.x + w.y * f2.y;
            #pragma unroll
            for (int s = 32; s; s >>= 1) d += __shfl_down(d, s, 64);
            if (lane == 0) weff[r] = d;
        }
        if (wave == 0) {
            float2 bb = ((const float2*)b2f)[lane];
            float d = bb.x * f2.x + bb.y * f2.y;
            #pragma unroll
            for (int s = 32; s; s >>= 1) d += __shfl_down(d, s, 64);
            if (lane == 0) weff[128] = d;
        }
        return;
    }
    {                                    // ---- wprep: swizzled bf16 weights ----
        int gid = (b - 2) * 1024 + tid;
        if (gid < 5 * 2048) {
            int mat = gid >> 11;
            int task = gid & 2047;
            int c = task >> 4, m = task & 15;
            const float* W = (mat == 0) ? W0 : (mat == 1) ? W1 : (mat == 2) ? W2 :
                             (mat == 3) ? W3 : W4;
            unsigned short* dp = Wswz + mat * 16384 + c * 128 + ((m ^ (c & 7)) << 3);
            #pragma unroll
            for (int j = 0; j < 8; ++j) dp[j] = f2bf(W[(8 * m + j) * FEAT + c]);
        }
    }
}

// FUSED per-bucket: self-computed prefix -> histogram -> wave scan -> off -> scatter.
__global__ __launch_bounds__(256) void degscat_kernel(
    const int* __restrict__ bcnt, const unsigned int* __restrict__ bpairs,
    int* __restrict__ off, int* __restrict__ srcs, int n, int E) {
    __shared__ int lh[64];
    __shared__ int lcur[64];
    int b = blockIdx.x, tid = threadIdx.x;
    if (tid < 64) lh[tid] = 0;
    if (b == 0 && tid == 0) off[n] = E;
    __syncthreads();
    int cnt = bcnt[b * 16]; if (cnt > BCAP) cnt = BCAP;
    const unsigned int* bp = bpairs + (size_t)b * BCAP;
    for (int i = tid; i < cnt; i += 256) atomicAdd(&lh[bp[i] & 63u], 1);
    __syncthreads();
    if (tid < 64) {
        // base = sum_{k<b} bcnt[k]  (<= 13 strided loads/lane + wave reduce)
        int bp_ = 0;
        for (int k = tid; k < b; k += 64) bp_ += bcnt[k * 16];
        #pragma unroll
        for (int d = 32; d; d >>= 1) bp_ += __shfl_down(bp_, d, 64);
        int base = __shfl(bp_, 0, 64);
        // exclusive scan over this bucket's 64 degrees
        int v = lh[tid];
        int inc = v;
        #pragma unroll
        for (int d = 1; d < 64; d <<= 1) {
            int u = __shfl_up(inc, d, 64);
            if (tid >= d) inc += u;
        }
        int ex = base + inc - v;
        int node = b * 64 + tid;
        if (node < n) off[node] = ex;
        lcur[tid] = ex;
    }
    __syncthreads();
    for (int i = tid; i < cnt; i += 256) {
        unsigned int pr = bp[i];
        int pos = atomicAdd(&lcur[pr & 63u], 1);
        srcs[pos] = (int)(pr >> 6);
    }
}

// ---------------- aggregation + (1+eps)*h -> sliced bf16 pre -----------------
__global__ __launch_bounds__(256) void agg_kernel(
    const unsigned int* __restrict__ hs, const int* __restrict__ off,
    const int* __restrict__ srcs, const float* __restrict__ eps_p,
    unsigned int* __restrict__ pre, int n) {
    int b = blockIdx.x;
    int slice = b & 3;
    int chunk = b >> 2;
    int tid = threadIdx.x;
    int wave = tid >> 6, lane = tid & 63;
    int g = lane >> 2, d = lane & 3;     // lane handles dwords 4d..4d+3
    int node = chunk * 64 + wave * 16 + g;
    if (node >= n) return;
    float eps1 = 1.0f + eps_p[0];
    const uint4* hb = (const uint4*)(hs + (size_t)slice * n * 16);  // row = 4 uint4
    uint4 su = hb[(size_t)node * 4 + d];
    float2 p0 = bfpair(su.x), p1 = bfpair(su.y), p2 = bfpair(su.z), p3 = bfpair(su.w);
    float4 a0 = make_float4(p0.x * eps1, p0.y * eps1, p1.x * eps1, p1.y * eps1);
    float4 b0 = make_float4(p2.x * eps1, p2.y * eps1, p3.x * eps1, p3.y * eps1);
    float4 a1 = make_float4(0.f, 0.f, 0.f, 0.f), b1v = a1;
    float4 a2 = a1, b2v = a1;
    float4 a3 = a1, b3v = a1;
    int j0 = off[node], j1 = off[node + 1];
    int j = j0;
    #define ACC(A, B, U) { float2 q0 = bfpair(U.x), q1 = bfpair(U.y), \
                                  q2 = bfpair(U.z), q3 = bfpair(U.w); \
        A.x += q0.x; A.y += q0.y; A.z += q1.x; A.w += q1.y; \
        B.x += q2.x; B.y += q2.y; B.z += q3.x; B.w += q3.y; }
    for (; j + 8 <= j1; j += 8) {
        int s0 = srcs[j], s1 = srcs[j + 1], s2 = srcs[j + 2], s3 = srcs[j + 3];
        int s4 = srcs[j + 4], s5 = srcs[j + 5], s6 = srcs[j + 6], s7 = srcs[j + 7];
        uint4 u0 = hb[(size_t)s0 * 4 + d];
        uint4 u1 = hb[(size_t)s1 * 4 + d];
        uint4 u2 = hb[(size_t)s2 * 4 + d];
        uint4 u3 = hb[(size_t)s3 * 4 + d];
        uint4 u4 = hb[(size_t)s4 * 4 + d];
        uint4 u5 = hb[(size_t)s5 * 4 + d];
        uint4 u6 = hb[(size_t)s6 * 4 + d];
        uint4 u7 = hb[(size_t)s7 * 4 + d];
        ACC(a0, b0, u0) ACC(a1, b1v, u1) ACC(a2, b2v, u2) ACC(a3, b3v, u3)
        ACC(a0, b0, u4) ACC(a1, b1v, u5) ACC(a2, b2v, u6) ACC(a3, b3v, u7)
    }
    for (; j + 4 <= j1; j += 4) {
        int s0 = srcs[j], s1 = srcs[j + 1], s2 = srcs[j + 2], s3 = srcs[j + 3];
        uint4 u0 = hb[(size_t)s0 * 4 + d];
        uint4 u1 = hb[(size_t)s1 * 4 + d];
        uint4 u2 = hb[(size_t)s2 * 4 + d];
        uint4 u3 = hb[(size_t)s3 * 4 + d];
        ACC(a0, b0, u0) ACC(a1, b1v, u1) ACC(a2, b2v, u2) ACC(a3, b3v, u3)
    }
    for (; j < j1; ++j) {
        uint4 u = hb[(size_t)srcs[j] * 4 + d];
        ACC(a0, b0, u)
    }
    #undef ACC
    a0.x += a1.x + a2.x;  a0.y += a1.y + a2.y;
    a0.z += a1.z + a2.z;  a0.w += a1.w + a2.w;
    a0.x += a3.x;  a0.y += a3.y;  a0.z += a3.z;  a0.w += a3.w;
    b0.x += b1v.x + b2v.x;  b0.y += b1v.y + b2v.y;
    b0.z += b1v.z + b2v.z;  b0.w += b1v.w + b2v.w;
    b0.x += b3v.x;  b0.y += b3v.y;  b0.z += b3v.z;  b0.w += b3v.w;
    uint4 o;
    o.x = (unsigned int)f2bf(a0.x) | ((unsigned int)f2bf(a0.y) << 16);
    o.y = (unsigned int)f2bf(a0.z) | ((unsigned int)f2bf(a0.w) << 16);
    o.z = (unsigned int)f2bf(b0.x) | ((unsigned int)f2bf(b0.y) << 16);
    o.w = (unsigned int)f2bf(b0.z) | ((unsigned int)f2bf(b0.w) << 16);
    ((uint4*)(pre + (size_t)slice * n * 16))[(size_t)node * 4 + d] = o;
}

// ---------------- bf16 MFMA GEMM over SLICED A. MODE 1: store. MODE 2: pool+finalize ----
template <int MODE>
__global__ __launch_bounds__(256) void mfma_mlp_kernel(
    const unsigned short* __restrict__ A, const unsigned short* __restrict__ Wswz,
    const float* __restrict__ bias, unsigned short* __restrict__ outbf,
    const int* __restrict__ batch, const float* __restrict__ weff,
    float* __restrict__ sums, int* __restrict__ donecnt,
    const int* __restrict__ gstart, const float* __restrict__ fcb,
    float* __restrict__ out, int G, int n) {
    __shared__ int4 Wl4[2048];   // 32KB swizzled W
    int tid = threadIdx.x;
    const int4* ws4 = (const int4*)Wswz;
    #pragma unroll
    for (int i = 0; i < 8; ++i) Wl4[i * 256 + tid] = ws4[i * 256 + tid];
    __syncthreads();
    const unsigned short* Wl = (const unsigned short*)Wl4;

    int lane = tid & 63, wave = tid >> 6;
    int q = lane >> 4, c15 = lane & 15;
    int r0 = blockIdx.x * 64 + wave * 16;
    int arow = r0 + c15;
    bool rv = arow < n;
    size_t sstride = (size_t)n * 32;     // shorts per slice
    const unsigned short* abase = A + (size_t)arow * 32 + 8 * q;

    f32x4 zf = {0.f, 0.f, 0.f, 0.f};
    f32x4 acc[8];
    #pragma unroll
    for (int i = 0; i < 8; ++i) acc[i] = zf;
    bf16x8 zero8 = {0, 0, 0, 0, 0, 0, 0, 0};

    #pragma unroll
    for (int k0 = 0; k0 < 4; ++k0) {
        bf16x8 a = rv ? *(const bf16x8*)(abase + (size_t)k0 * sstride) : zero8;
        int m = k0 * 4 + q;
        #pragma unroll
        for (int nt = 0; nt < 8; ++nt) {
            int col = nt * 16 + c15;
            bf16x8 bfr = *(const bf16x8*)&Wl[col * 128 + ((m ^ (col & 7)) << 3)];
            acc[nt] = __builtin_amdgcn_mfma_f32_16x16x32_bf16(a, bfr, acc[nt], 0, 0, 0);
        }
    }

    int orow0 = r0 + q * 4;
    if (MODE == 1) {
        #pragma unroll
        for (int nt = 0; nt < 8; ++nt) {
            float bv = bias[nt * 16 + c15];
            size_t sb = (size_t)(nt >> 1) * sstride + (nt & 1) * 16 + c15;
            #pragma unroll
            for (int r = 0; r < 4; ++r) {
                int ro = orow0 + r;
                if (ro < n) {
                    float v = fmaxf(acc[nt][r] + bv, 0.f);
                    outbf[sb + (size_t)ro * 32] = f2bf(v);
                }
            }
        }
    } else {
        // fused pool: rowdot = relu(row)·weff ; per-graph LDS accumulation.
        __shared__ float gsum[64];
        __shared__ int amlast;
        int r0b = blockIdx.x * 64;
        int lastn = r0b + 63 < n - 1 ? r0b + 63 : n - 1;
        int gmin = batch[r0b];
        int gmax = batch[lastn];
        int span = gmax - gmin + 1;
        bool lds_ok = (span <= 64);
        if (lds_ok) for (int i = tid; i < span; i += 256) gsum[i] = 0.f;
        __syncthreads();
        float rowdot[4] = {0.f, 0.f, 0.f, 0.f};
        #pragma unroll
        for (int nt = 0; nt < 8; ++nt) {
            int col = nt * 16 + c15;
            float bv = bias[col];
            float wv = weff[col];
            #pragma unroll
            for (int r = 0; r < 4; ++r)
                rowdot[r] += fmaxf(acc[nt][r] + bv, 0.f) * wv;
        }
        #pragma unroll
        for (int r = 0; r < 4; ++r) {
            float v = rowdot[r];
            v += __shfl_xor(v, 1, 64);
            v += __shfl_xor(v, 2, 64);
            v += __shfl_xor(v, 4, 64);
            v += __shfl_xor(v, 8, 64);
            if (c15 == 0) {
                int node = orow0 + r;
                if (node < n) {
                    int g = batch[node];
                    if (lds_ok) atomicAdd(&gsum[g - gmin], v);
                    else        atomicAdd(&sums[g], v);
                }
            }
        }
        __syncthreads();
        if (lds_ok)
            for (int i = tid; i < span; i += 256) atomicAdd(&sums[gmin + i], gsum[i]);
        // last-block finalize: out[g] = sums/cnt + b2.fcw + fcb
        __threadfence();
        __syncthreads();
        if (tid == 0) amlast = (atomicAdd(donecnt, 1) == (int)gridDim.x - 1) ? 1 : 0;
        __syncthreads();
        if (amlast) {
            for (int g = tid; g < G; g += 256) {
                int cg = gstart[g + 1] - gstart[g];
                float sv = ((volatile float*)sums)[g];
                out[g] = (cg > 0) ? sv / (float)cg + weff[128] + fcb[0] : fcb[0];
            }
        }
    }
}

static inline size_t align256(size_t x) { return (x + 255) & ~(size_t)255; }

extern "C" void kernel_launch(void* const* d_in, const int* in_sizes, int n_in,
                              void* d_out, int out_size, void* d_ws, size_t ws_size,
                              hipStream_t stream) {
    const float* x      = (const float*)d_in[0];
    const int*   ei     = (const int*)d_in[1];
    const int*   batch  = (const int*)d_in[2];
    const float* W1[3]  = {(const float*)d_in[3],  (const float*)d_in[8],  (const float*)d_in[13]};
    const float* b1[3]  = {(const float*)d_in[4],  (const float*)d_in[9],  (const float*)d_in[14]};
    const float* W2[3]  = {(const float*)d_in[5],  (const float*)d_in[10], (const float*)d_in[15]};
    const float* b2[3]  = {(const float*)d_in[6],  (const float*)d_in[11], (const float*)d_in[16]};
    const float* eps[3] = {(const float*)d_in[7],  (const float*)d_in[12], (const float*)d_in[17]};
    const float* fcw    = (const float*)d_in[18];
    const float* fcb    = (const float*)d_in[19];
    float* out = (float*)d_out;

    const int N = in_sizes[0] / FEAT;
    const int E = in_sizes[1] / 2;
    const int G = out_size;
    const int nbuckets = (N + 63) >> 6;

    // workspace layout
    char* p = (char*)d_ws;
    int* off    = (int*)p;  p += align256((size_t)(N + 1) * 4);
    int* srcs   = (int*)p;  p += align256((size_t)E * 4);
    int* gstart = (int*)p;  p += align256((size_t)(G + 1) * 4);
    float* weff = (float*)p; p += align256((size_t)256 * 4);
    unsigned short* Wswz = (unsigned short*)p; p += align256((size_t)5 * 16384 * 2);
    float* sums = (float*)p;                     // zero-init region start
    char* z0 = (char*)sums;
    p += align256((size_t)G * 4);
    int* donecnt = (int*)p; p += align256(256);
    int* bcnt = (int*)p; p += align256((size_t)nbuckets * 16 * 4);
    size_t zbytes = (size_t)(p - z0);            // sums + donecnt + bcnt in one memset
    unsigned int* bpairs = (unsigned int*)p;     p += align256((size_t)nbuckets * BCAP * 4);
    unsigned int* x_bf   = (unsigned int*)p;     p += align256((size_t)N * 64 * 4);
    unsigned int* pre_bf = (unsigned int*)p;     p += align256((size_t)N * 64 * 4);
    unsigned int* t_bf   = (unsigned int*)p;     p += align256((size_t)N * 64 * 4);
    unsigned int* h_bf   = (unsigned int*)p;     p += align256((size_t)N * 64 * 4);
    (void)ws_size; (void)n_in;

    const int* src = ei;        // edge_index[0]
    const int* dst = ei + E;    // edge_index[1]

    hipMemsetAsync(z0, 0, zbytes, stream);

    // front: bucket (nchunks blocks) + xbf + gstart + weff + wprep, one dispatch
    const int nchunks = (E + CHUNK - 1) / CHUNK;
    long pairs = (long)N * 64;
    int nxbf = (int)((pairs + 1023) / 1024);
    front_kernel<<<nchunks + nxbf + 2 + 10, 1024, 0, stream>>>(
        src, dst, bcnt, bpairs, E, nchunks,
        x, x_bf, pairs, nxbf, batch, gstart, N, G,
        W2[2], b2[2], fcw, weff,
        W1[0], W2[0], W1[1], W2[1], W1[2], Wswz);

    // fused degscat (self-computed prefix)
    degscat_kernel<<<nbuckets, 256, 0, stream>>>(bcnt, bpairs, off, srcs, N, E);

    const int aggBlocks  = 4 * ((N + 63) / 64);   // 4 slices, 64 nodes/block
    const int gemmBlocks = (N + 63) / 64;
    const unsigned short* Wz[5] = {Wswz, Wswz + 16384, Wswz + 2 * 16384,
                                   Wswz + 3 * 16384, Wswz + 4 * 16384};

    // layers 0,1: agg -> gemm1(sliced bf16) -> gemm2(sliced bf16)
    const unsigned int* h = x_bf;
    for (int i = 0; i < 2; ++i) {
        agg_kernel<<<aggBlocks, 256, 0, stream>>>(h, off, srcs, eps[i], pre_bf, N);
        mfma_mlp_kernel<1><<<gemmBlocks, 256, 0, stream>>>(
            (const unsigned short*)pre_bf, Wz[2 * i], b1[i], (unsigned short*)t_bf,
            nullptr, nullptr, nullptr, nullptr, nullptr, nullptr, nullptr, 0, N);
        mfma_mlp_kernel<1><<<gemmBlocks, 256, 0, stream>>>(
            (const unsigned short*)t_bf, Wz[2 * i + 1], b2[i], (unsigned short*)h_bf,
            nullptr, nullptr, nullptr, nullptr, nullptr, nullptr, nullptr, 0, N);
        h = h_bf;
    }
    // layer 2: agg -> gemm1 with fused pooled-dot epilogue + last-block finalize
    agg_kernel<<<aggBlocks, 256, 0, stream>>>(h, off, srcs, eps[2], pre_bf, N);
    mfma_mlp_kernel<2><<<gemmBlocks, 256, 0, stream>>>(
        (const unsigned short*)pre_bf, Wz[4], b1[2], nullptr,
        batch, weff, sums, donecnt, gstart, fcb, out, G, N);
}